// Round 5
// baseline (310.610 us; speedup 1.0000x reference)
//
#include <hip/hip_runtime.h>
#include <math.h>

// Problem constants (fixed by reference file)
#define NB   2
#define LQ   16384
#define CDIM 256
#define MH   8          // heads
#define DH   32         // head dim
#define LIN  21760      // 128^2+64^2+32^2+16^2

typedef __attribute__((ext_vector_type(8))) short bf16x8;
typedef __attribute__((ext_vector_type(4))) float f32x4;

// split f32 -> bf16 hi (truncate) + bf16 lo (residual, truncate); a ~= hi+lo, err ~2^-16|a|
__device__ __forceinline__ void split_bf16(float a, unsigned short& hi, unsigned short& lo) {
    unsigned int u = __float_as_uint(a);
    hi = (unsigned short)(u >> 16);
    float hf = __uint_as_float(u & 0xFFFF0000u);
    float l  = a - hf;
    lo = (unsigned short)(__float_as_uint(l) >> 16);
}

// async 16B global->LDS (wave-uniform LDS base + lane*16 — no padding allowed)
__device__ __forceinline__ void async16(const unsigned short* g, unsigned short* l) {
    __builtin_amdgcn_global_load_lds(
        (__attribute__((address_space(1))) void*)g,
        (__attribute__((address_space(3))) void*)l,
        16, 0, 0);
}

// ---------------- pre-split: f32 array -> hi/lo bf16 planes ----------------
__global__ __launch_bounds__(256) void split_kernel(
    const float* __restrict__ in, unsigned short* __restrict__ hi,
    unsigned short* __restrict__ lo, int n8)
{
    const int i = blockIdx.x * 256 + threadIdx.x;
    if (i >= n8) return;
    const float4 v0 = ((const float4*)in)[i * 2];
    const float4 v1 = ((const float4*)in)[i * 2 + 1];
    union { unsigned short s[8]; uint4 v; } ph, pl;
    split_bf16(v0.x, ph.s[0], pl.s[0]);
    split_bf16(v0.y, ph.s[1], pl.s[1]);
    split_bf16(v0.z, ph.s[2], pl.s[2]);
    split_bf16(v0.w, ph.s[3], pl.s[3]);
    split_bf16(v1.x, ph.s[4], pl.s[4]);
    split_bf16(v1.y, ph.s[5], pl.s[5]);
    split_bf16(v1.z, ph.s[6], pl.s[6]);
    split_bf16(v1.w, ph.s[7], pl.s[7]);
    ((uint4*)hi)[i] = ph.v;
    ((uint4*)lo)[i] = pl.v;
}

// transpose-split weights: W is K=256 x N (row-major) -> out[n][k] hi/lo bf16
__global__ __launch_bounds__(256) void tsplit_kernel(
    const float* __restrict__ W, unsigned short* __restrict__ th,
    unsigned short* __restrict__ tl, int N)
{
    const int i = blockIdx.x * 256 + threadIdx.x;   // over N*256
    if (i >= N * 256) return;
    const int nn = i >> 8;       // 0..N-1
    const int kk = i & 255;      // 0..255
    split_bf16(W[kk * N + nn], th[i], tl[i]);
}

// ---------------- pre-split bf16x3 MFMA GEMM (m97-style staging) ----------------
// C = A @ B + bias, A: MxK f32 pre-split (Ah/Al bf16 row-major), B given
// TRANSPOSED pre-split: Bth/Btl are [N][K] bf16. Tile 128x128x32, 256 thr.
// 3-term emulation: acc += Al*Bh + Ah*Bl + Ah*Bh.
// Output routing: cols < N0 -> C0 (ld N0, bias0); cols >= N0 -> C1 (ld N-N0, bias1).
__global__ __launch_bounds__(256) void gemm_pre(
    const unsigned short* __restrict__ Ah, const unsigned short* __restrict__ Al,
    const unsigned short* __restrict__ Bth, const unsigned short* __restrict__ Btl,
    const float* __restrict__ bias0, const float* __restrict__ bias1,
    float* __restrict__ C0, float* __restrict__ C1,
    int M, int N, int K, int N0)
{
    __shared__ unsigned short Ash[128 * 32];   // [row][k], unpadded (global_load_lds)
    __shared__ unsigned short Asl[128 * 32];
    __shared__ unsigned short Bsh[128 * 32];   // [n][k]
    __shared__ unsigned short Bsl[128 * 32];

    const int tid  = threadIdx.x;
    const int wave = tid >> 6, lane = tid & 63;
    const int quad = lane >> 4, l16 = lane & 15;
    const int bm = blockIdx.y * 128;
    const int bn = blockIdx.x * 128;
    const int wrow = wave * 32;

    f32x4 acc[2][8] = {};

    const int s0 = tid,        row0 = s0 >> 2, kg0 = (s0 & 3) << 3;
    const int s1 = tid + 256,  row1 = s1 >> 2, kg1 = (s1 & 3) << 3;

    for (int k0 = 0; k0 < K; k0 += 32) {
        const size_t ga0 = (size_t)(bm + row0) * K + k0 + kg0;
        const size_t ga1 = (size_t)(bm + row1) * K + k0 + kg1;
        const size_t gb0 = (size_t)(bn + row0) * K + k0 + kg0;
        const size_t gb1 = (size_t)(bn + row1) * K + k0 + kg1;
        async16(Ah  + ga0, Ash + s0 * 8);
        async16(Ah  + ga1, Ash + s1 * 8);
        async16(Al  + ga0, Asl + s0 * 8);
        async16(Al  + ga1, Asl + s1 * 8);
        async16(Bth + gb0, Bsh + s0 * 8);
        async16(Bth + gb1, Bsh + s1 * 8);
        async16(Btl + gb0, Bsl + s0 * 8);
        async16(Btl + gb1, Bsl + s1 * 8);
        __syncthreads();   // compiler emits vmcnt(0) drain here

        bf16x8 ah[2], al[2];
        #pragma unroll
        for (int r = 0; r < 2; ++r) {
            const int mrow = wrow + r * 16 + l16;
            ah[r] = *(const bf16x8*)&Ash[mrow * 32 + quad * 8];
            al[r] = *(const bf16x8*)&Asl[mrow * 32 + quad * 8];
        }
        #pragma unroll
        for (int half = 0; half < 2; ++half) {
            bf16x8 bh[4], bl[4];
            #pragma unroll
            for (int c = 0; c < 4; ++c) {
                const int ncol = half * 64 + c * 16 + l16;
                bh[c] = *(const bf16x8*)&Bsh[ncol * 32 + quad * 8];
                bl[c] = *(const bf16x8*)&Bsl[ncol * 32 + quad * 8];
            }
            #pragma unroll
            for (int r = 0; r < 2; ++r)
                #pragma unroll
                for (int c = 0; c < 4; ++c) {
                    f32x4 a = acc[r][half * 4 + c];
                    a = __builtin_amdgcn_mfma_f32_16x16x32_bf16(al[r], bh[c], a, 0, 0, 0);
                    a = __builtin_amdgcn_mfma_f32_16x16x32_bf16(ah[r], bl[c], a, 0, 0, 0);
                    a = __builtin_amdgcn_mfma_f32_16x16x32_bf16(ah[r], bh[c], a, 0, 0, 0);
                    acc[r][half * 4 + c] = a;
                }
        }
        __syncthreads();
    }

    // epilogue: C/D layout col=lane&15 (from B-frag), row=quad*4+reg (r4-verified)
    float* Cb; const float* bb; int ldc, coff;
    if (bn < N0) { Cb = C0; bb = bias0; ldc = N0;     coff = 0;  }
    else         { Cb = C1; bb = bias1; ldc = N - N0; coff = N0; }
    #pragma unroll
    for (int c = 0; c < 8; ++c) {
        const int col = bn + c * 16 + l16 - coff;
        const float bia = bb[col];
        #pragma unroll
        for (int r = 0; r < 2; ++r)
            #pragma unroll
            for (int i = 0; i < 4; ++i) {
                const int rr = bm + wrow + r * 16 + quad * 4 + i;
                Cb[(size_t)rr * ldc + col] = acc[r][c][i] + bia;
            }
    }
}

// ---------------- sampling v4: fused softmax + pipelined gather, bf16 out ----
// Block = 256 threads, 4 queries.
// Phase 1: 512 tasks (q,m,pt): lane pt reads logit[p*4+l] (transposed pairing
//   — softmax max/sum are permutation-invariant so 16-lane shfl reduction is
//   unaffected), computes softmax weight + corner weights/indices -> LDS.
// Phase 2: thread (q,m,d4) owns 4 channels; depth-2 pipelined gather+FMA.
// Output written pre-split (hi/lo bf16 planes) for the out-GEMM.
__global__ __launch_bounds__(256) void sample_kernel_v4(
    const float* __restrict__ value,
    const float* __restrict__ off,      // (N*LQ, 256)
    const float* __restrict__ attnlog,  // (N*LQ, 128) raw logits
    unsigned short* __restrict__ outh,
    unsigned short* __restrict__ outl)
{
    __shared__ __align__(16) float lds_task[8][516];

    const int tid = threadIdx.x;
    const int qbase = blockIdx.x * 4;

    #pragma unroll
    for (int j = 0; j < 2; ++j) {
        const int t  = tid + 256 * j;
        const int q  = t >> 7;
        const int m  = (t >> 4) & 7;
        const int pt = t & 15;          // pt = l*4 + p
        const int l  = pt >> 2;
        const int p  = pt & 3;
        const int qi = qbase + q;
        const int lq = qi & (LQ - 1);
        const int n  = qi >> 14;

        const int Hl = 128 >> l;
        const int STARTS[4] = {0, 16384, 20480, 21504};

        const float2 oxy = *(const float2*)&off[(size_t)qi * 256 + m * 32 + pt * 2];
        const float lg = attnlog[(size_t)qi * 128 + m * 16 + (p * 4 + l)];

        // fused softmax over the 16-lane (q,m) group
        float mx = lg;
        #pragma unroll
        for (int s = 1; s < 16; s <<= 1) mx = fmaxf(mx, __shfl_xor(mx, s));
        const float e = __expf(lg - mx);
        float sum = e;
        #pragma unroll
        for (int s = 1; s < 16; s <<= 1) sum += __shfl_xor(sum, s);
        const float w = e / sum;

        const float refx = ((lq & 127) + 0.5f) * (1.0f / 128.0f);
        const float refy = ((lq >> 7)  + 0.5f) * (1.0f / 128.0f);

        const float x = refx * (float)Hl + oxy.x - 0.5f;
        const float y = refy * (float)Hl + oxy.y - 0.5f;
        const float x0f = floorf(x), y0f = floorf(y);
        const int x0 = (int)x0f, y0 = (int)y0f;
        const int x1 = x0 + 1,  y1 = y0 + 1;
        const float fx = x - x0f, fy = y - y0f;
        const float gx = 1.f - fx, gy = 1.f - fy;

        const float vx0 = (x0 >= 0 && x0 < Hl) ? 1.f : 0.f;
        const float vx1 = (x1 >= 0 && x1 < Hl) ? 1.f : 0.f;
        const float vy0 = (y0 >= 0 && y0 < Hl) ? 1.f : 0.f;
        const float vy1 = (y1 >= 0 && y1 < Hl) ? 1.f : 0.f;

        const int x0c = min(max(x0, 0), Hl - 1);
        const int x1c = min(max(x1, 0), Hl - 1);
        const int y0c = min(max(y0, 0), Hl - 1);
        const int y1c = min(max(y1, 0), Hl - 1);

        const int base = (n * LIN + STARTS[l]) * 256 + m * 32;
        const int i00 = base + (y0c * Hl + x0c) * 256;
        const int i01 = base + (y0c * Hl + x1c) * 256;
        const int i10 = base + (y1c * Hl + x0c) * 256;
        const int i11 = base + (y1c * Hl + x1c) * 256;

        float4 wv;
        wv.x = w * gy * gx * vy0 * vx0;
        wv.y = w * gy * fx * vy0 * vx1;
        wv.z = w * fy * gx * vy1 * vx0;
        wv.w = w * fy * fx * vy1 * vx1;

        float* dst = &lds_task[m][(q * 16 + pt) * 8];
        *(float4*)dst = wv;
        int4 iv = {i00, i01, i10, i11};
        *(int4*)(dst + 4) = iv;
    }
    __syncthreads();

    // ---- Phase 2: depth-2 pipelined gather + weighted accumulate ----
    const int q  = tid >> 6;
    const int m  = (tid >> 3) & 7;
    const int d4 = tid & 7;
    const int qi = qbase + q;

    const float* vbase = value + d4 * 4;

    const float* td0 = &lds_task[m][(q * 16 + 0) * 8];
    float4 wv = *(const float4*)td0;
    int4  iv  = *(const int4*)(td0 + 4);
    float4 v00 = *(const float4*)&vbase[iv.x];
    float4 v01 = *(const float4*)&vbase[iv.y];
    float4 v10 = *(const float4*)&vbase[iv.z];
    float4 v11 = *(const float4*)&vbase[iv.w];

    float4 acc = {0.f, 0.f, 0.f, 0.f};
    #pragma unroll
    for (int pt = 0; pt < 16; ++pt) {
        const float4 wc = wv;
        const float4 c00 = v00, c01 = v01, c10 = v10, c11 = v11;
        if (pt < 15) {
            const float* td = &lds_task[m][(q * 16 + pt + 1) * 8];
            wv = *(const float4*)td;
            iv = *(const int4*)(td + 4);
            v00 = *(const float4*)&vbase[iv.x];
            v01 = *(const float4*)&vbase[iv.y];
            v10 = *(const float4*)&vbase[iv.z];
            v11 = *(const float4*)&vbase[iv.w];
        }
        acc.x += wc.x * c00.x + wc.y * c01.x + wc.z * c10.x + wc.w * c11.x;
        acc.y += wc.x * c00.y + wc.y * c01.y + wc.z * c10.y + wc.w * c11.y;
        acc.z += wc.x * c00.z + wc.y * c01.z + wc.z * c10.z + wc.w * c11.z;
        acc.w += wc.x * c00.w + wc.y * c01.w + wc.z * c10.w + wc.w * c11.w;
    }

    // write pre-split bf16 planes (same total bytes as f32)
    union { unsigned short s[4]; uint2 v; } uh, ul;
    split_bf16(acc.x, uh.s[0], ul.s[0]);
    split_bf16(acc.y, uh.s[1], ul.s[1]);
    split_bf16(acc.z, uh.s[2], ul.s[2]);
    split_bf16(acc.w, uh.s[3], ul.s[3]);
    const size_t ob = (size_t)qi * 256 + m * 32 + d4 * 4;
    *(uint2*)&outh[ob] = uh.v;
    *(uint2*)&outl[ob] = ul.v;
}

// ---------------- launch ----------------
extern "C" void kernel_launch(void* const* d_in, const int* in_sizes, int n_in,
                              void* d_out, int out_size, void* d_ws, size_t ws_size,
                              hipStream_t stream)
{
    const float* query         = (const float*)d_in[0];
    const float* input_flatten = (const float*)d_in[2];
    const float* W_off  = (const float*)d_in[5];
    const float* b_off  = (const float*)d_in[6];
    const float* W_attn = (const float*)d_in[7];
    const float* b_attn = (const float*)d_in[8];
    const float* W_val  = (const float*)d_in[9];
    const float* b_val  = (const float*)d_in[10];
    const float* W_out  = (const float*)d_in[11];
    const float* b_out  = (const float*)d_in[12];
    float* out = (float*)d_out;

    // Workspace (106.8 MB peak). Region1 (44.56 MB) is time-shared:
    //   IFh/IFl  -> consumed by value GEMM
    //   Qh/Ql    -> consumed by offattn GEMM
    //   Sh/Sl    -> written by sample, consumed by out GEMM
    // (stream-serial kernels make the lifetimes disjoint)
    char* w = (char*)d_ws;
    unsigned short* IFh = (unsigned short*)w;                  // 11,141,120 shorts
    unsigned short* IFl = IFh + 11141120;
    unsigned short* Qh  = (unsigned short*)w;                  // 8,388,608 shorts
    unsigned short* Ql  = Qh + 8388608;
    unsigned short* Sh  = (unsigned short*)w;
    unsigned short* Sl  = Sh + 8388608;
    float* value   = (float*)(w + 44564480);                   // 43520x256 f32
    float* attnbuf = (float*)(w + 89128960);                   // 32768x128 f32 logits
    unsigned short* Wvh = (unsigned short*)(w + 105906176);    // [256][256]
    unsigned short* Wvl = Wvh + 65536;
    unsigned short* Woh = Wvl + 65536;
    unsigned short* Wol = Woh + 65536;
    unsigned short* Wch = Wol + 65536;                         // [384][256] (off|attn)
    unsigned short* Wcl = Wch + 98304;
    float* offbuf = out;   // off staged in d_out, consumed before final GEMM

    dim3 blk(256);

    // weights: transpose-split (tiny)
    tsplit_kernel<<<256, blk, 0, stream>>>(W_val, Wvh, Wvl, 256);
    tsplit_kernel<<<256, blk, 0, stream>>>(W_out, Woh, Wol, 256);
    tsplit_kernel<<<256, blk, 0, stream>>>(W_off, Wch, Wcl, 256);
    tsplit_kernel<<<128, blk, 0, stream>>>(W_attn, Wch + 65536, Wcl + 65536, 128);

    // 1) split input_flatten; value = IF @ W_val + b_val
    split_kernel<<<(1392640 + 255) / 256, blk, 0, stream>>>(input_flatten, IFh, IFl, 1392640);
    gemm_pre<<<dim3(2, 340), blk, 0, stream>>>(IFh, IFl, Wvh, Wvl, b_val, b_val,
                                               value, value, 43520, 256, 256, 256);

    // 2) split query; fused off|attn GEMM (N=384, routed epilogue)
    split_kernel<<<(1048576 + 255) / 256, blk, 0, stream>>>(query, Qh, Ql, 1048576);
    gemm_pre<<<dim3(3, 256), blk, 0, stream>>>(Qh, Ql, Wch, Wcl, b_off, b_attn,
                                               offbuf, attnbuf, 32768, 384, 256, 256);

    // 3) sampling (fused softmax) -> pre-split sampled planes
    sample_kernel_v4<<<8192, blk, 0, stream>>>(value, offbuf, attnbuf, Sh, Sl);

    // 4) out = sampled @ W_out + b_out
    gemm_pre<<<dim3(2, 256), blk, 0, stream>>>(Sh, Sl, Woh, Wol, b_out, b_out,
                                               out, out, 32768, 256, 256, 256);
}

// Round 6
// 300.729 us; speedup vs baseline: 1.0329x; 1.0329x over previous
//
#include <hip/hip_runtime.h>
#include <math.h>

// Problem constants (fixed by reference file)
#define NB   2
#define LQ   16384
#define CDIM 256
#define MH   8          // heads
#define DH   32         // head dim
#define LIN  21760      // 128^2+64^2+32^2+16^2

typedef __attribute__((ext_vector_type(8))) short    bf16x8;
typedef __attribute__((ext_vector_type(8))) _Float16 f16x8;
typedef __attribute__((ext_vector_type(4))) _Float16 f16x4;
typedef __attribute__((ext_vector_type(4))) float    f32x4;

// split f32 -> bf16 hi (truncate) + bf16 lo (residual, truncate); a ~= hi+lo, err ~2^-16|a|
__device__ __forceinline__ void split_bf16(float a, unsigned short& hi, unsigned short& lo) {
    unsigned int u = __float_as_uint(a);
    hi = (unsigned short)(u >> 16);
    float hf = __uint_as_float(u & 0xFFFF0000u);
    float l  = a - hf;
    lo = (unsigned short)(__float_as_uint(l) >> 16);
}

// async 16B global->LDS (wave-uniform LDS base + lane*16 — no padding allowed)
__device__ __forceinline__ void async16(const void* g, void* l) {
    __builtin_amdgcn_global_load_lds(
        (const __attribute__((address_space(1))) void*)g,
        (__attribute__((address_space(3))) void*)l,
        16, 0, 0);
}

// ---------------- pre-split: f32 -> hi/lo bf16 planes (for off/attn GEMM) ----
__global__ __launch_bounds__(256) void split_kernel(
    const float* __restrict__ in, unsigned short* __restrict__ hi,
    unsigned short* __restrict__ lo, int n8)
{
    const int i = blockIdx.x * 256 + threadIdx.x;
    if (i >= n8) return;
    const float4 v0 = ((const float4*)in)[i * 2];
    const float4 v1 = ((const float4*)in)[i * 2 + 1];
    union { unsigned short s[8]; uint4 v; } ph, pl;
    split_bf16(v0.x, ph.s[0], pl.s[0]);
    split_bf16(v0.y, ph.s[1], pl.s[1]);
    split_bf16(v0.z, ph.s[2], pl.s[2]);
    split_bf16(v0.w, ph.s[3], pl.s[3]);
    split_bf16(v1.x, ph.s[4], pl.s[4]);
    split_bf16(v1.y, ph.s[5], pl.s[5]);
    split_bf16(v1.z, ph.s[6], pl.s[6]);
    split_bf16(v1.w, ph.s[7], pl.s[7]);
    ((uint4*)hi)[i] = ph.v;
    ((uint4*)lo)[i] = pl.v;
}

// f32 -> f16 single plane (for value / out GEMM A-operands)
__global__ __launch_bounds__(256) void split_f16_kernel(
    const float* __restrict__ in, _Float16* __restrict__ o, int n8)
{
    const int i = blockIdx.x * 256 + threadIdx.x;
    if (i >= n8) return;
    const float4 v0 = ((const float4*)in)[i * 2];
    const float4 v1 = ((const float4*)in)[i * 2 + 1];
    f16x8 h;
    h[0] = (_Float16)v0.x; h[1] = (_Float16)v0.y;
    h[2] = (_Float16)v0.z; h[3] = (_Float16)v0.w;
    h[4] = (_Float16)v1.x; h[5] = (_Float16)v1.y;
    h[6] = (_Float16)v1.z; h[7] = (_Float16)v1.w;
    ((f16x8*)o)[i] = h;
}

// transpose-split weights: W[k][n] f32 -> out[n][k] hi/lo bf16
__global__ __launch_bounds__(256) void tsplit_kernel(
    const float* __restrict__ W, unsigned short* __restrict__ th,
    unsigned short* __restrict__ tl, int N)
{
    const int i = blockIdx.x * 256 + threadIdx.x;
    if (i >= N * 256) return;
    const int nn = i >> 8;
    const int kk = i & 255;
    split_bf16(W[kk * N + nn], th[i], tl[i]);
}

// transpose weights to f16: W[k][n] f32 -> out[n][k] f16
__global__ __launch_bounds__(256) void tsplit_f16_kernel(
    const float* __restrict__ W, _Float16* __restrict__ t, int N)
{
    const int i = blockIdx.x * 256 + threadIdx.x;
    if (i >= N * 256) return;
    const int nn = i >> 8;
    const int kk = i & 255;
    t[i] = (_Float16)W[kk * N + nn];
}

// ---------------- single-term f16 MFMA GEMM ----------------
// C = A @ B + bias. A: MxK f16 row-major. Bt: [N][K] f16 (pre-transposed).
// Tile 128x128x32, 256 threads, 16 mfma_f32_16x16x32_f16 per iter.
// OUT_F16: write C as f16 (value GEMM) else f32 (out GEMM).
template <bool OUT_F16>
__global__ __launch_bounds__(256) void gemm_f16(
    const _Float16* __restrict__ A, const _Float16* __restrict__ Bt,
    const float* __restrict__ bias, void* __restrict__ C,
    int M, int N, int K)
{
    __shared__ _Float16 Ash[128 * 32];   // [row][k], unpadded (global_load_lds)
    __shared__ _Float16 Bsh[128 * 32];   // [n][k]

    const int tid  = threadIdx.x;
    const int wave = tid >> 6, lane = tid & 63;
    const int quad = lane >> 4, l16 = lane & 15;
    const int bm = blockIdx.y * 128;
    const int bn = blockIdx.x * 128;
    const int wrow = wave * 32;

    f32x4 acc[2][8] = {};

    const int s0 = tid,        row0 = s0 >> 2, kg0 = (s0 & 3) << 3;
    const int s1 = tid + 256,  row1 = s1 >> 2, kg1 = (s1 & 3) << 3;

    for (int k0 = 0; k0 < K; k0 += 32) {
        async16(A  + (size_t)(bm + row0) * K + k0 + kg0, Ash + s0 * 8);
        async16(A  + (size_t)(bm + row1) * K + k0 + kg1, Ash + s1 * 8);
        async16(Bt + (size_t)(bn + row0) * K + k0 + kg0, Bsh + s0 * 8);
        async16(Bt + (size_t)(bn + row1) * K + k0 + kg1, Bsh + s1 * 8);
        __syncthreads();

        f16x8 ah[2];
        #pragma unroll
        for (int r = 0; r < 2; ++r)
            ah[r] = *(const f16x8*)&Ash[(wrow + r * 16 + l16) * 32 + quad * 8];
        #pragma unroll
        for (int half = 0; half < 2; ++half) {
            f16x8 bh[4];
            #pragma unroll
            for (int c = 0; c < 4; ++c)
                bh[c] = *(const f16x8*)&Bsh[(half * 64 + c * 16 + l16) * 32 + quad * 8];
            #pragma unroll
            for (int r = 0; r < 2; ++r)
                #pragma unroll
                for (int c = 0; c < 4; ++c)
                    acc[r][half * 4 + c] = __builtin_amdgcn_mfma_f32_16x16x32_f16(
                        ah[r], bh[c], acc[r][half * 4 + c], 0, 0, 0);
        }
        __syncthreads();
    }

    // epilogue: C/D layout col=lane&15, row=quad*4+reg (HW-verified mapping)
    #pragma unroll
    for (int c = 0; c < 8; ++c) {
        const int col = bn + c * 16 + l16;
        const float bia = bias[col];
        #pragma unroll
        for (int r = 0; r < 2; ++r)
            #pragma unroll
            for (int i = 0; i < 4; ++i) {
                const int rr = bm + wrow + r * 16 + quad * 4 + i;
                const float v = acc[r][c][i] + bia;
                if (OUT_F16) ((_Float16*)C)[(size_t)rr * N + col] = (_Float16)v;
                else         ((float*)C)[(size_t)rr * N + col] = v;
            }
    }
}

// ---------------- bf16x3 MFMA GEMM, pre-split, routed epilogue (off|attn) ----
__global__ __launch_bounds__(256) void gemm_pre(
    const unsigned short* __restrict__ Ah, const unsigned short* __restrict__ Al,
    const unsigned short* __restrict__ Bth, const unsigned short* __restrict__ Btl,
    const float* __restrict__ bias0, const float* __restrict__ bias1,
    float* __restrict__ C0, float* __restrict__ C1,
    int M, int N, int K, int N0)
{
    __shared__ unsigned short Ash[128 * 32];
    __shared__ unsigned short Asl[128 * 32];
    __shared__ unsigned short Bsh[128 * 32];
    __shared__ unsigned short Bsl[128 * 32];

    const int tid  = threadIdx.x;
    const int wave = tid >> 6, lane = tid & 63;
    const int quad = lane >> 4, l16 = lane & 15;
    const int bm = blockIdx.y * 128;
    const int bn = blockIdx.x * 128;
    const int wrow = wave * 32;

    f32x4 acc[2][8] = {};

    const int s0 = tid,        row0 = s0 >> 2, kg0 = (s0 & 3) << 3;
    const int s1 = tid + 256,  row1 = s1 >> 2, kg1 = (s1 & 3) << 3;

    for (int k0 = 0; k0 < K; k0 += 32) {
        const size_t ga0 = (size_t)(bm + row0) * K + k0 + kg0;
        const size_t ga1 = (size_t)(bm + row1) * K + k0 + kg1;
        const size_t gb0 = (size_t)(bn + row0) * K + k0 + kg0;
        const size_t gb1 = (size_t)(bn + row1) * K + k0 + kg1;
        async16(Ah  + ga0, Ash + s0 * 8);
        async16(Ah  + ga1, Ash + s1 * 8);
        async16(Al  + ga0, Asl + s0 * 8);
        async16(Al  + ga1, Asl + s1 * 8);
        async16(Bth + gb0, Bsh + s0 * 8);
        async16(Bth + gb1, Bsh + s1 * 8);
        async16(Btl + gb0, Bsl + s0 * 8);
        async16(Btl + gb1, Bsl + s1 * 8);
        __syncthreads();

        bf16x8 ah[2], al[2];
        #pragma unroll
        for (int r = 0; r < 2; ++r) {
            const int mrow = wrow + r * 16 + l16;
            ah[r] = *(const bf16x8*)&Ash[mrow * 32 + quad * 8];
            al[r] = *(const bf16x8*)&Asl[mrow * 32 + quad * 8];
        }
        #pragma unroll
        for (int half = 0; half < 2; ++half) {
            bf16x8 bh[4], bl[4];
            #pragma unroll
            for (int c = 0; c < 4; ++c) {
                const int ncol = half * 64 + c * 16 + l16;
                bh[c] = *(const bf16x8*)&Bsh[ncol * 32 + quad * 8];
                bl[c] = *(const bf16x8*)&Bsl[ncol * 32 + quad * 8];
            }
            #pragma unroll
            for (int r = 0; r < 2; ++r)
                #pragma unroll
                for (int c = 0; c < 4; ++c) {
                    f32x4 a = acc[r][half * 4 + c];
                    a = __builtin_amdgcn_mfma_f32_16x16x32_bf16(al[r], bh[c], a, 0, 0, 0);
                    a = __builtin_amdgcn_mfma_f32_16x16x32_bf16(ah[r], bl[c], a, 0, 0, 0);
                    a = __builtin_amdgcn_mfma_f32_16x16x32_bf16(ah[r], bh[c], a, 0, 0, 0);
                    acc[r][half * 4 + c] = a;
                }
        }
        __syncthreads();
    }

    float* Cb; const float* bb; int ldc, coff;
    if (bn < N0) { Cb = C0; bb = bias0; ldc = N0;     coff = 0;  }
    else         { Cb = C1; bb = bias1; ldc = N - N0; coff = N0; }
    #pragma unroll
    for (int c = 0; c < 8; ++c) {
        const int col = bn + c * 16 + l16 - coff;
        const float bia = bb[col];
        #pragma unroll
        for (int r = 0; r < 2; ++r)
            #pragma unroll
            for (int i = 0; i < 4; ++i) {
                const int rr = bm + wrow + r * 16 + quad * 4 + i;
                Cb[(size_t)rr * ldc + col] = acc[r][c][i] + bia;
            }
    }
}

// ---------------- softmax over last-16, in place ----------------
__global__ __launch_bounds__(256) void softmax16_kernel(float* __restrict__ a, int rows)
{
    const int r = blockIdx.x * 256 + threadIdx.x;
    if (r >= rows) return;
    float* row = a + (size_t)r * 16;
    float v[16];
    float4* rv = (float4*)row;
    #pragma unroll
    for (int i = 0; i < 4; ++i) *(float4*)&v[i * 4] = rv[i];
    float mx = v[0];
    #pragma unroll
    for (int i = 1; i < 16; ++i) mx = fmaxf(mx, v[i]);
    float s = 0.f;
    #pragma unroll
    for (int i = 0; i < 16; ++i) { v[i] = __expf(v[i] - mx); s += v[i]; }
    const float inv = 1.f / s;
    #pragma unroll
    for (int i = 0; i < 16; ++i) v[i] *= inv;
    #pragma unroll
    for (int i = 0; i < 4; ++i) rv[i] = *(float4*)&v[i * 4];
}

// ---------------- sampling v5: two-phase, f16 value taps, f16 out ----------------
// Block = 256 threads, 4 queries.
// Phase 1: 512 tasks (q,m,pt) -> LDS: 4 combined corner weights + 4 indices.
// Phase 2: thread (q,m,d4): depth-2 pipelined f16x4 gathers + f32 FMA.
// Reference quirk preserved: sample (l,p) weighted by attn[..., p, l].
__global__ __launch_bounds__(256) void sample_kernel_v5(
    const _Float16* __restrict__ value,
    const float* __restrict__ off,      // (N*LQ, 256)
    const float* __restrict__ attn,     // (N*LQ, 128) softmaxed
    _Float16* __restrict__ outv)
{
    __shared__ __align__(16) float lds_task[8][516];

    const int tid = threadIdx.x;
    const int qbase = blockIdx.x * 4;

    #pragma unroll
    for (int j = 0; j < 2; ++j) {
        const int t  = tid + 256 * j;
        const int q  = t >> 7;
        const int m  = (t >> 4) & 7;
        const int pt = t & 15;          // pt = l*4 + p
        const int l  = pt >> 2;
        const int p  = pt & 3;
        const int qi = qbase + q;
        const int lq = qi & (LQ - 1);
        const int n  = qi >> 14;

        const int Hl = 128 >> l;
        const int STARTS[4] = {0, 16384, 20480, 21504};

        const float2 oxy = *(const float2*)&off[(size_t)qi * 256 + m * 32 + pt * 2];
        const float w    = attn[(size_t)qi * 128 + m * 16 + p * 4 + l]; // transposed pairing

        const float refx = ((lq & 127) + 0.5f) * (1.0f / 128.0f);
        const float refy = ((lq >> 7)  + 0.5f) * (1.0f / 128.0f);

        const float x = refx * (float)Hl + oxy.x - 0.5f;
        const float y = refy * (float)Hl + oxy.y - 0.5f;
        const float x0f = floorf(x), y0f = floorf(y);
        const int x0 = (int)x0f, y0 = (int)y0f;
        const int x1 = x0 + 1,  y1 = y0 + 1;
        const float fx = x - x0f, fy = y - y0f;
        const float gx = 1.f - fx, gy = 1.f - fy;

        const float vx0 = (x0 >= 0 && x0 < Hl) ? 1.f : 0.f;
        const float vx1 = (x1 >= 0 && x1 < Hl) ? 1.f : 0.f;
        const float vy0 = (y0 >= 0 && y0 < Hl) ? 1.f : 0.f;
        const float vy1 = (y1 >= 0 && y1 < Hl) ? 1.f : 0.f;

        const int x0c = min(max(x0, 0), Hl - 1);
        const int x1c = min(max(x1, 0), Hl - 1);
        const int y0c = min(max(y0, 0), Hl - 1);
        const int y1c = min(max(y1, 0), Hl - 1);

        const int base = (n * LIN + STARTS[l]) * 256 + m * 32;
        const int i00 = base + (y0c * Hl + x0c) * 256;
        const int i01 = base + (y0c * Hl + x1c) * 256;
        const int i10 = base + (y1c * Hl + x0c) * 256;
        const int i11 = base + (y1c * Hl + x1c) * 256;

        float4 wv;
        wv.x = w * gy * gx * vy0 * vx0;
        wv.y = w * gy * fx * vy0 * vx1;
        wv.z = w * fy * gx * vy1 * vx0;
        wv.w = w * fy * fx * vy1 * vx1;

        float* dst = &lds_task[m][(q * 16 + pt) * 8];
        *(float4*)dst = wv;
        int4 iv = {i00, i01, i10, i11};
        *(int4*)(dst + 4) = iv;
    }
    __syncthreads();

    // ---- Phase 2: depth-2 pipelined f16 gather + f32 accumulate ----
    const int q  = tid >> 6;
    const int m  = (tid >> 3) & 7;
    const int d4 = tid & 7;
    const int qi = qbase + q;

    const _Float16* vbase = value + d4 * 4;

    const float* td0 = &lds_task[m][(q * 16 + 0) * 8];
    float4 wv = *(const float4*)td0;
    int4  iv  = *(const int4*)(td0 + 4);
    f16x4 v00 = *(const f16x4*)&vbase[iv.x];
    f16x4 v01 = *(const f16x4*)&vbase[iv.y];
    f16x4 v10 = *(const f16x4*)&vbase[iv.z];
    f16x4 v11 = *(const f16x4*)&vbase[iv.w];

    float4 acc = {0.f, 0.f, 0.f, 0.f};
    #pragma unroll
    for (int pt = 0; pt < 16; ++pt) {
        const float4 wc = wv;
        const f16x4 c00 = v00, c01 = v01, c10 = v10, c11 = v11;
        if (pt < 15) {
            const float* td = &lds_task[m][(q * 16 + pt + 1) * 8];
            wv = *(const float4*)td;
            iv = *(const int4*)(td + 4);
            v00 = *(const f16x4*)&vbase[iv.x];
            v01 = *(const f16x4*)&vbase[iv.y];
            v10 = *(const f16x4*)&vbase[iv.z];
            v11 = *(const f16x4*)&vbase[iv.w];
        }
        acc.x += wc.x * (float)c00.x + wc.y * (float)c01.x + wc.z * (float)c10.x + wc.w * (float)c11.x;
        acc.y += wc.x * (float)c00.y + wc.y * (float)c01.y + wc.z * (float)c10.y + wc.w * (float)c11.y;
        acc.z += wc.x * (float)c00.z + wc.y * (float)c01.z + wc.z * (float)c10.z + wc.w * (float)c11.z;
        acc.w += wc.x * (float)c00.w + wc.y * (float)c01.w + wc.z * (float)c10.w + wc.w * (float)c11.w;
    }

    f16x4 o;
    o.x = (_Float16)acc.x; o.y = (_Float16)acc.y;
    o.z = (_Float16)acc.z; o.w = (_Float16)acc.w;
    *(f16x4*)&outv[(size_t)qi * 256 + m * 32 + d4 * 4] = o;
}

// ---------------- launch ----------------
extern "C" void kernel_launch(void* const* d_in, const int* in_sizes, int n_in,
                              void* d_out, int out_size, void* d_ws, size_t ws_size,
                              hipStream_t stream)
{
    const float* query         = (const float*)d_in[0];
    const float* input_flatten = (const float*)d_in[2];
    const float* W_off  = (const float*)d_in[5];
    const float* b_off  = (const float*)d_in[6];
    const float* W_attn = (const float*)d_in[7];
    const float* b_attn = (const float*)d_in[8];
    const float* W_val  = (const float*)d_in[9];
    const float* b_val  = (const float*)d_in[10];
    const float* W_out  = (const float*)d_in[11];
    const float* b_out  = (const float*)d_in[12];
    float* out = (float*)d_out;

    // Workspace (~74 MB peak). Region1 (33.5 MB @ 0) is time-shared:
    //   IFf16 (22.3 MB) -> consumed by value GEMM
    //   Qh/Ql (33.5 MB) -> consumed by offattn GEMM
    //   Sf16  (16.8 MB) -> written by sample, consumed by out GEMM
    // (stream-serial kernels make the lifetimes disjoint)
    char* w = (char*)d_ws;
    _Float16*       IFf16 = (_Float16*)w;
    unsigned short* Qh    = (unsigned short*)w;
    unsigned short* Ql    = Qh + 8388608;
    _Float16*       Sf16  = (_Float16*)w;
    _Float16*       value = (_Float16*)(w + 33554432);          // 43520x256 f16
    float*          attnbuf = (float*)(w + 55836672);           // 32768x128 f32
    _Float16*       Wvt  = (_Float16*)(w + 72613888);           // [256][256] f16
    _Float16*       Wot  = Wvt + 65536;
    unsigned short* Wch  = (unsigned short*)(Wot + 65536);      // [384][256] bf16 hi
    unsigned short* Wcl  = Wch + 98304;                         // lo
    float* offbuf = out;   // off staged in d_out, consumed before final GEMM

    dim3 blk(256);

    // weight transforms (tiny)
    tsplit_f16_kernel<<<256, blk, 0, stream>>>(W_val, Wvt, 256);
    tsplit_f16_kernel<<<256, blk, 0, stream>>>(W_out, Wot, 256);
    tsplit_kernel<<<256, blk, 0, stream>>>(W_off, Wch, Wcl, 256);
    tsplit_kernel<<<128, blk, 0, stream>>>(W_attn, Wch + 65536, Wcl + 65536, 128);

    // 1) IF -> f16; value(f16) = IF @ W_val + b_val
    split_f16_kernel<<<(1392640 + 255) / 256, blk, 0, stream>>>(input_flatten, IFf16, 1392640);
    gemm_f16<true><<<dim3(2, 340), blk, 0, stream>>>(IFf16, Wvt, b_val, value, 43520, 256, 256);

    // 2) query -> hi/lo bf16; fused off|attn GEMM (bf16x3, routed epilogue)
    split_kernel<<<(1048576 + 255) / 256, blk, 0, stream>>>(query, Qh, Ql, 1048576);
    gemm_pre<<<dim3(3, 256), blk, 0, stream>>>(Qh, Ql, Wch, Wcl, b_off, b_attn,
                                               offbuf, attnbuf, 32768, 384, 256, 256);

    // 3) softmax over 16 per (n,lq,m)
    softmax16_kernel<<<1024, blk, 0, stream>>>(attnbuf, 262144);

    // 4) sampling: f16 taps -> f16 sampled
    sample_kernel_v5<<<8192, blk, 0, stream>>>(value, offbuf, attnbuf, Sf16);

    // 5) out = sampled @ W_out + b_out (f16 MFMA, f32 out)
    gemm_f16<false><<<dim3(2, 256), blk, 0, stream>>>(Sf16, Wot, b_out, out, 32768, 256, 256);
}

// Round 7
// 276.931 us; speedup vs baseline: 1.1216x; 1.0859x over previous
//
#include <hip/hip_runtime.h>
#include <math.h>

// Problem constants (fixed by reference file)
#define NB   2
#define LQ   16384
#define CDIM 256
#define MH   8          // heads
#define DH   32         // head dim
#define LIN  21760      // 128^2+64^2+32^2+16^2

typedef __attribute__((ext_vector_type(8))) _Float16 f16x8;
typedef __attribute__((ext_vector_type(4))) _Float16 f16x4;
typedef __attribute__((ext_vector_type(4))) float    f32x4;

// async 16B global->LDS (wave-uniform LDS base + lane*16 — no padding allowed)
__device__ __forceinline__ void async16(const void* g, void* l) {
    __builtin_amdgcn_global_load_lds(
        (const __attribute__((address_space(1))) void*)g,
        (__attribute__((address_space(3))) void*)l,
        16, 0, 0);
}

// ---------------- f32 -> f16 plane (GEMM A-operands) ----------------
__global__ __launch_bounds__(256) void split_f16_kernel(
    const float* __restrict__ in, _Float16* __restrict__ o, int n8)
{
    const int i = blockIdx.x * 256 + threadIdx.x;
    if (i >= n8) return;
    const float4 v0 = ((const float4*)in)[i * 2];
    const float4 v1 = ((const float4*)in)[i * 2 + 1];
    f16x8 h;
    h[0] = (_Float16)v0.x; h[1] = (_Float16)v0.y;
    h[2] = (_Float16)v0.z; h[3] = (_Float16)v0.w;
    h[4] = (_Float16)v1.x; h[5] = (_Float16)v1.y;
    h[6] = (_Float16)v1.z; h[7] = (_Float16)v1.w;
    ((f16x8*)o)[i] = h;
}

// transpose weights to f16: W[k][n] f32 -> out[n][k] f16
__global__ __launch_bounds__(256) void tsplit_f16_kernel(
    const float* __restrict__ W, _Float16* __restrict__ t, int N)
{
    const int i = blockIdx.x * 256 + threadIdx.x;
    if (i >= N * 256) return;
    const int nn = i >> 8;
    const int kk = i & 255;
    t[i] = (_Float16)W[kk * N + nn];
}

// ---------------- single-term f16 MFMA GEMM, routed epilogue ----------------
// C = A @ B + bias. A: MxK f16 row-major. Bt: [N][K] f16 (pre-transposed).
// Tile 128x128x32, 256 threads, 16 mfma_f32_16x16x32_f16 per iter.
// Output routing: cols < N0 -> C0 (ld N0, bias0); cols >= N0 -> C1 (ld N-N0, bias1).
// OUT_F16: write f16, else f32.
template <bool OUT_F16>
__global__ __launch_bounds__(256) void gemm_f16(
    const _Float16* __restrict__ A, const _Float16* __restrict__ Bt,
    const float* __restrict__ bias0, const float* __restrict__ bias1,
    void* __restrict__ C0, void* __restrict__ C1,
    int M, int N, int K, int N0)
{
    __shared__ _Float16 Ash[128 * 32];   // [row][k], unpadded (global_load_lds)
    __shared__ _Float16 Bsh[128 * 32];   // [n][k]

    const int tid  = threadIdx.x;
    const int wave = tid >> 6, lane = tid & 63;
    const int quad = lane >> 4, l16 = lane & 15;
    const int bm = blockIdx.y * 128;
    const int bn = blockIdx.x * 128;
    const int wrow = wave * 32;

    f32x4 acc[2][8] = {};

    const int s0 = tid,        row0 = s0 >> 2, kg0 = (s0 & 3) << 3;
    const int s1 = tid + 256,  row1 = s1 >> 2, kg1 = (s1 & 3) << 3;

    for (int k0 = 0; k0 < K; k0 += 32) {
        async16(A  + (size_t)(bm + row0) * K + k0 + kg0, Ash + s0 * 8);
        async16(A  + (size_t)(bm + row1) * K + k0 + kg1, Ash + s1 * 8);
        async16(Bt + (size_t)(bn + row0) * K + k0 + kg0, Bsh + s0 * 8);
        async16(Bt + (size_t)(bn + row1) * K + k0 + kg1, Bsh + s1 * 8);
        __syncthreads();

        f16x8 ah[2];
        #pragma unroll
        for (int r = 0; r < 2; ++r)
            ah[r] = *(const f16x8*)&Ash[(wrow + r * 16 + l16) * 32 + quad * 8];
        #pragma unroll
        for (int half = 0; half < 2; ++half) {
            f16x8 bh[4];
            #pragma unroll
            for (int c = 0; c < 4; ++c)
                bh[c] = *(const f16x8*)&Bsh[(half * 64 + c * 16 + l16) * 32 + quad * 8];
            #pragma unroll
            for (int r = 0; r < 2; ++r)
                #pragma unroll
                for (int c = 0; c < 4; ++c)
                    acc[r][half * 4 + c] = __builtin_amdgcn_mfma_f32_16x16x32_f16(
                        ah[r], bh[c], acc[r][half * 4 + c], 0, 0, 0);
        }
        __syncthreads();
    }

    // epilogue: C/D layout col=lane&15, row=quad*4+reg (HW-verified mapping)
    void* Cb; const float* bb; int ldc, coff;
    if (bn < N0) { Cb = C0; bb = bias0; ldc = N0;     coff = 0;  }
    else         { Cb = C1; bb = bias1; ldc = N - N0; coff = N0; }
    #pragma unroll
    for (int c = 0; c < 8; ++c) {
        const int col = bn + c * 16 + l16 - coff;
        const float bia = bb[col];
        #pragma unroll
        for (int r = 0; r < 2; ++r)
            #pragma unroll
            for (int i = 0; i < 4; ++i) {
                const int rr = bm + wrow + r * 16 + quad * 4 + i;
                const float v = acc[r][c][i] + bia;
                if (OUT_F16) ((_Float16*)Cb)[(size_t)rr * ldc + col] = (_Float16)v;
                else         ((float*)Cb)[(size_t)rr * ldc + col] = v;
            }
    }
}

// ---------------- softmax over last-16, in place ----------------
__global__ __launch_bounds__(256) void softmax16_kernel(float* __restrict__ a, int rows)
{
    const int r = blockIdx.x * 256 + threadIdx.x;
    if (r >= rows) return;
    float* row = a + (size_t)r * 16;
    float v[16];
    float4* rv = (float4*)row;
    #pragma unroll
    for (int i = 0; i < 4; ++i) *(float4*)&v[i * 4] = rv[i];
    float mx = v[0];
    #pragma unroll
    for (int i = 1; i < 16; ++i) mx = fmaxf(mx, v[i]);
    float s = 0.f;
    #pragma unroll
    for (int i = 0; i < 16; ++i) { v[i] = __expf(v[i] - mx); s += v[i]; }
    const float inv = 1.f / s;
    #pragma unroll
    for (int i = 0; i < 16; ++i) v[i] *= inv;
    #pragma unroll
    for (int i = 0; i < 4; ++i) rv[i] = *(float4*)&v[i * 4];
}

// ---------------- sampling v6: v3 structure (champion), f16 output ----------------
// Block = 256 threads, 4 queries.
// Phase 1: 512 tasks (q,m,pt) -> LDS: 4 combined corner weights + 4 indices.
// Phase 2: thread (q,m,d4) owns 4 channels; simple gather+FMA loop (no explicit
//   pipeline — v4/v5 showed it regresses), writes f16.
// Reference quirk preserved: sample (l,p) weighted by attn[..., p, l].
__global__ __launch_bounds__(256) void sample_kernel_v6(
    const float* __restrict__ value,
    const float* __restrict__ off,      // (N*LQ, 256)
    const float* __restrict__ attn,     // (N*LQ, 128) softmaxed
    _Float16* __restrict__ outv)
{
    __shared__ __align__(16) float lds_task[8][516];

    const int tid = threadIdx.x;
    const int qbase = blockIdx.x * 4;

    #pragma unroll
    for (int j = 0; j < 2; ++j) {
        const int t  = tid + 256 * j;
        const int q  = t >> 7;
        const int m  = (t >> 4) & 7;
        const int pt = t & 15;          // pt = l*4 + p
        const int l  = pt >> 2;
        const int p  = pt & 3;
        const int qi = qbase + q;
        const int lq = qi & (LQ - 1);
        const int n  = qi >> 14;

        const int Hl = 128 >> l;
        const int STARTS[4] = {0, 16384, 20480, 21504};

        const float2 oxy = *(const float2*)&off[(size_t)qi * 256 + m * 32 + pt * 2];
        const float w    = attn[(size_t)qi * 128 + m * 16 + p * 4 + l]; // transposed pairing

        const float refx = ((lq & 127) + 0.5f) * (1.0f / 128.0f);
        const float refy = ((lq >> 7)  + 0.5f) * (1.0f / 128.0f);

        const float x = refx * (float)Hl + oxy.x - 0.5f;
        const float y = refy * (float)Hl + oxy.y - 0.5f;
        const float x0f = floorf(x), y0f = floorf(y);
        const int x0 = (int)x0f, y0 = (int)y0f;
        const int x1 = x0 + 1,  y1 = y0 + 1;
        const float fx = x - x0f, fy = y - y0f;
        const float gx = 1.f - fx, gy = 1.f - fy;

        const float vx0 = (x0 >= 0 && x0 < Hl) ? 1.f : 0.f;
        const float vx1 = (x1 >= 0 && x1 < Hl) ? 1.f : 0.f;
        const float vy0 = (y0 >= 0 && y0 < Hl) ? 1.f : 0.f;
        const float vy1 = (y1 >= 0 && y1 < Hl) ? 1.f : 0.f;

        const int x0c = min(max(x0, 0), Hl - 1);
        const int x1c = min(max(x1, 0), Hl - 1);
        const int y0c = min(max(y0, 0), Hl - 1);
        const int y1c = min(max(y1, 0), Hl - 1);

        const int base = (n * LIN + STARTS[l]) * 256 + m * 32;
        const int i00 = base + (y0c * Hl + x0c) * 256;
        const int i01 = base + (y0c * Hl + x1c) * 256;
        const int i10 = base + (y1c * Hl + x0c) * 256;
        const int i11 = base + (y1c * Hl + x1c) * 256;

        float4 wv;
        wv.x = w * gy * gx * vy0 * vx0;
        wv.y = w * gy * fx * vy0 * vx1;
        wv.z = w * fy * gx * vy1 * vx0;
        wv.w = w * fy * fx * vy1 * vx1;

        float* dst = &lds_task[m][(q * 16 + pt) * 8];
        *(float4*)dst = wv;
        int4 iv = {i00, i01, i10, i11};
        *(int4*)(dst + 4) = iv;
    }
    __syncthreads();

    // ---- Phase 2: gather + weighted accumulate (simple loop) ----
    const int q  = tid >> 6;
    const int m  = (tid >> 3) & 7;
    const int d4 = tid & 7;
    const int qi = qbase + q;

    const float* vbase = value + d4 * 4;

    float4 acc = {0.f, 0.f, 0.f, 0.f};
    #pragma unroll
    for (int pt = 0; pt < 16; ++pt) {
        const float* td = &lds_task[m][(q * 16 + pt) * 8];
        const float4 wv = *(const float4*)td;
        const int4  iv = *(const int4*)(td + 4);
        const float4 v00 = *(const float4*)&vbase[iv.x];
        const float4 v01 = *(const float4*)&vbase[iv.y];
        const float4 v10 = *(const float4*)&vbase[iv.z];
        const float4 v11 = *(const float4*)&vbase[iv.w];
        acc.x += wv.x * v00.x + wv.y * v01.x + wv.z * v10.x + wv.w * v11.x;
        acc.y += wv.x * v00.y + wv.y * v01.y + wv.z * v10.y + wv.w * v11.y;
        acc.z += wv.x * v00.z + wv.y * v01.z + wv.z * v10.z + wv.w * v11.z;
        acc.w += wv.x * v00.w + wv.y * v01.w + wv.z * v10.w + wv.w * v11.w;
    }

    f16x4 o;
    o.x = (_Float16)acc.x; o.y = (_Float16)acc.y;
    o.z = (_Float16)acc.z; o.w = (_Float16)acc.w;
    *(f16x4*)&outv[(size_t)qi * 256 + m * 32 + d4 * 4] = o;
}

// ---------------- launch ----------------
extern "C" void kernel_launch(void* const* d_in, const int* in_sizes, int n_in,
                              void* d_out, int out_size, void* d_ws, size_t ws_size,
                              hipStream_t stream)
{
    const float* query         = (const float*)d_in[0];
    const float* input_flatten = (const float*)d_in[2];
    const float* W_off  = (const float*)d_in[5];
    const float* b_off  = (const float*)d_in[6];
    const float* W_attn = (const float*)d_in[7];
    const float* b_attn = (const float*)d_in[8];
    const float* W_val  = (const float*)d_in[9];
    const float* b_val  = (const float*)d_in[10];
    const float* W_out  = (const float*)d_in[11];
    const float* b_out  = (const float*)d_in[12];
    float* out = (float*)d_out;

    // Workspace (~84 MB peak). Region1 (22.3 MB @ 0) is time-shared
    // under the launch ORDER below (stream-serial => disjoint lifetimes):
    //   IFf16 (22.3 MB): written by split, consumed by value GEMM
    //   Qf16  (16.8 MB): written after value GEMM, consumed by offattn GEMM
    //   Sf16  (16.8 MB): written by sampler, consumed by out GEMM
    char* w = (char*)d_ws;
    _Float16* IFf16 = (_Float16*)w;
    _Float16* Qf16  = (_Float16*)w;
    _Float16* Sf16  = (_Float16*)w;
    float*    value   = (float*)(w + 23068672);        // 43520x256 f32 (44.6 MB)
    float*    attnbuf = (float*)(w + 67633152);        // 32768x128 f32 (16.8 MB)
    _Float16* Wvt = (_Float16*)(w + 84410368);         // [256][256] f16
    _Float16* Wot = Wvt + 65536;                       // [256][256] f16
    _Float16* Wct = Wot + 65536;                       // [384][256] f16 (off|attn)
    float* offbuf = out;   // off staged in d_out, consumed before final GEMM

    dim3 blk(256);

    // weight transforms (tiny)
    tsplit_f16_kernel<<<256, blk, 0, stream>>>(W_val, Wvt, 256);
    tsplit_f16_kernel<<<256, blk, 0, stream>>>(W_out, Wot, 256);
    tsplit_f16_kernel<<<256, blk, 0, stream>>>(W_off, Wct, 256);
    tsplit_f16_kernel<<<128, blk, 0, stream>>>(W_attn, Wct + 65536, 128);

    // 1) IF -> f16; value(f32) = IF @ W_val + b_val
    split_f16_kernel<<<(1392640 + 255) / 256, blk, 0, stream>>>(input_flatten, IFf16, 1392640);
    gemm_f16<false><<<dim3(2, 340), blk, 0, stream>>>(
        IFf16, Wvt, b_val, b_val, value, value, 43520, 256, 256, 256);

    // 2) query -> f16; fused off|attn GEMM (routed epilogue, f32 out)
    split_f16_kernel<<<(1048576 + 255) / 256, blk, 0, stream>>>(query, Qf16, 1048576);
    gemm_f16<false><<<dim3(3, 256), blk, 0, stream>>>(
        Qf16, Wct, b_off, b_attn, offbuf, attnbuf, 32768, 384, 256, 256);

    // 3) softmax over 16 per (n,lq,m)
    softmax16_kernel<<<1024, blk, 0, stream>>>(attnbuf, 262144);

    // 4) sampling: f32 taps -> f16 sampled
    sample_kernel_v6<<<8192, blk, 0, stream>>>(value, offbuf, attnbuf, Sf16);

    // 5) out = sampled @ W_out + b_out (f16 MFMA, f32 out)
    gemm_f16<false><<<dim3(2, 256), blk, 0, stream>>>(
        Sf16, Wot, b_out, b_out, out, out, 32768, 256, 256, 256);
}